// Round 1
// baseline (359.796 us; speedup 1.0000x reference)
//
#include <hip/hip_runtime.h>
#include <hip/hip_fp16.h>
#include <stdint.h>

typedef _Float16 half_t;
typedef __attribute__((ext_vector_type(8))) _Float16 half8;   // 4 VGPRs (MFMA A/B frag)
typedef __attribute__((ext_vector_type(4))) float  f32x4;     // MFMA C/D frag
typedef __attribute__((ext_vector_type(4))) float  float4v;

#define BM 128
#define BN 128
#define BK 32

// ---------------------------------------------------------------------------
// Pass 1: fp32 -> fp16 RNE quantize.  (float)(_Float16)v == reference quantize
// (e5m10, RNE, denormals handled by HW cvt). Vectorized 8 elems/thread.
// ---------------------------------------------------------------------------
__global__ void quant_f32_to_f16(const float* __restrict__ in,
                                 half_t* __restrict__ out, long n) {
    long i = ((long)blockIdx.x * blockDim.x + threadIdx.x) * 8;
    if (i + 8 <= n) {
        float4v v0 = *(const float4v*)(in + i);
        float4v v1 = *(const float4v*)(in + i + 4);
        half8 h;
        h[0] = (half_t)v0[0]; h[1] = (half_t)v0[1];
        h[2] = (half_t)v0[2]; h[3] = (half_t)v0[3];
        h[4] = (half_t)v1[0]; h[5] = (half_t)v1[1];
        h[6] = (half_t)v1[2]; h[7] = (half_t)v1[3];
        *(half8*)(out + i) = h;
    } else {
        for (; i < n; ++i) out[i] = (half_t)in[i];
    }
}

// ---------------------------------------------------------------------------
// async 16B global -> LDS copy (dest must be wave-uniform base + lane*16)
// ---------------------------------------------------------------------------
__device__ __forceinline__ void gld_lds16(const void* g, void* l) {
    __builtin_amdgcn_global_load_lds(
        (const __attribute__((address_space(1))) void*)g,
        (__attribute__((address_space(3))) void*)l, 16, 0, 0);
}

// ---------------------------------------------------------------------------
// GEMM: C[m][n] = sum_k A[m][k]*B[n][k] + q(bias[n])
// Both operands K-contiguous (B^T form). 128x128 tile, BK=32, 4 waves (2x2,
// 64x64 each), mfma_f32_16x16x32_f16, m97 structure.
// FUSED=true: A/B are fp32, converted during staging (no workspace needed).
// FUSED=false: A/B are pre-quantized fp16 in d_ws, staged via global_load_lds.
// ---------------------------------------------------------------------------
template <bool FUSED>
__global__ __launch_bounds__(256)
void gemm_qf16(const void* __restrict__ Av, const void* __restrict__ Bv,
               const float* __restrict__ bias, float* __restrict__ C,
               int M, int N, int K) {
    __shared__ half_t sA[BM * BK];   // 8 KB, no padding (global_load_lds rule)
    __shared__ half_t sB[BN * BK];   // 8 KB

    const int t    = threadIdx.x;
    const int lane = t & 63;
    const int wave = t >> 6;
    const int wm   = (wave >> 1) * 64;   // wave row offset in tile
    const int wn   = (wave & 1) * 64;    // wave col offset in tile

    const int bm = blockIdx.y * BM;
    const int bn = blockIdx.x * BN;

    // staging: 512 16B-chunks per tile; chunk c -> row c>>2, k-chunk c&3
    const int c0 = t, c1 = t + 256;
    const int r0 = c0 >> 2, kc0 = c0 & 3;
    const int r1 = c1 >> 2, kc1 = c1 & 3;

    f32x4 acc[4][4] = {};

    const int kg = (lane >> 4) * 8;  // A/B-operand k-group: k = quad*8 + j
    const int rr = lane & 15;        // A row / B col within 16

    for (int k0 = 0; k0 < K; k0 += BK) {
        if constexpr (!FUSED) {
            const half_t* A = (const half_t*)Av;
            const half_t* B = (const half_t*)Bv;
            gld_lds16(A + (long)(bm + r0) * K + k0 + kc0 * 8, &sA[c0 * 8]);
            gld_lds16(A + (long)(bm + r1) * K + k0 + kc1 * 8, &sA[c1 * 8]);
            gld_lds16(B + (long)(bn + r0) * K + k0 + kc0 * 8, &sB[c0 * 8]);
            gld_lds16(B + (long)(bn + r1) * K + k0 + kc1 * 8, &sB[c1 * 8]);
        } else {
            const float* A = (const float*)Av;
            const float* B = (const float*)Bv;
            #pragma unroll
            for (int s = 0; s < 2; ++s) {
                const int c  = s ? c1 : c0;
                const int rw = s ? r1 : r0;
                const int kc = s ? kc1 : kc0;
                const float* ga = A + (long)(bm + rw) * K + k0 + kc * 8;
                const float* gb = B + (long)(bn + rw) * K + k0 + kc * 8;
                float4v a0 = *(const float4v*)ga;
                float4v a1 = *(const float4v*)(ga + 4);
                float4v b0 = *(const float4v*)gb;
                float4v b1 = *(const float4v*)(gb + 4);
                half8 ha, hb;
                ha[0]=(half_t)a0[0]; ha[1]=(half_t)a0[1]; ha[2]=(half_t)a0[2]; ha[3]=(half_t)a0[3];
                ha[4]=(half_t)a1[0]; ha[5]=(half_t)a1[1]; ha[6]=(half_t)a1[2]; ha[7]=(half_t)a1[3];
                hb[0]=(half_t)b0[0]; hb[1]=(half_t)b0[1]; hb[2]=(half_t)b0[2]; hb[3]=(half_t)b0[3];
                hb[4]=(half_t)b1[0]; hb[5]=(half_t)b1[1]; hb[6]=(half_t)b1[2]; hb[7]=(half_t)b1[3];
                *(half8*)&sA[c * 8] = ha;
                *(half8*)&sB[c * 8] = hb;
            }
        }
        __syncthreads();

        half8 af[4], bf[4];
        #pragma unroll
        for (int i = 0; i < 4; ++i) {
            af[i] = *(const half8*)&sA[(wm + i * 16 + rr) * BK + kg];
            bf[i] = *(const half8*)&sB[(wn + i * 16 + rr) * BK + kg];
        }
        #pragma unroll
        for (int i = 0; i < 4; ++i)
            #pragma unroll
            for (int j = 0; j < 4; ++j)
                acc[i][j] = __builtin_amdgcn_mfma_f32_16x16x32_f16(
                    af[i], bf[j], acc[i][j], 0, 0, 0);
        __syncthreads();
    }

    // Epilogue: C/D layout col = lane&15, row = (lane>>4)*4 + reg  [m89/m91]
    const int r4 = (lane >> 4) * 4;
    const int cc = lane & 15;
    #pragma unroll
    for (int j = 0; j < 4; ++j) {
        const int col = bn + wn + j * 16 + cc;
        const float bq = (float)(half_t)bias[col];   // inline bias quantize
        #pragma unroll
        for (int i = 0; i < 4; ++i) {
            const int rowb = bm + wm + i * 16 + r4;
            #pragma unroll
            for (int r = 0; r < 4; ++r)
                C[(long)(rowb + r) * N + col] = acc[i][j][r] + bq;
        }
    }
}

extern "C" void kernel_launch(void* const* d_in, const int* in_sizes, int n_in,
                              void* d_out, int out_size, void* d_ws, size_t ws_size,
                              hipStream_t stream) {
    const float* x    = (const float*)d_in[0];
    const float* w    = (const float*)d_in[1];
    const float* bias = (const float*)d_in[2];
    float* out = (float*)d_out;

    const int OUT = in_sizes[2];
    const int IN  = in_sizes[1] / OUT;
    const int M   = in_sizes[0] / IN;
    const int N   = OUT, K = IN;

    dim3 grid(N / BN, M / BM);
    const size_t needed = ((size_t)M * K + (size_t)N * K) * sizeof(half_t);

    if (ws_size >= needed) {
        half_t* qa = (half_t*)d_ws;
        half_t* qb = qa + (size_t)M * K;
        const long na = (long)M * K, nb = (long)N * K;
        const int tb = 256;
        quant_f32_to_f16<<<(int)((na / 8 + tb - 1) / tb), tb, 0, stream>>>(x, qa, na);
        quant_f32_to_f16<<<(int)((nb / 8 + tb - 1) / tb), tb, 0, stream>>>(w, qb, nb);
        gemm_qf16<false><<<grid, 256, 0, stream>>>(qa, qb, bias, out, M, N, K);
    } else {
        gemm_qf16<true><<<grid, 256, 0, stream>>>(x, w, bias, out, M, N, K);
    }
}

// Round 2
// 318.989 us; speedup vs baseline: 1.1279x; 1.1279x over previous
//
#include <hip/hip_runtime.h>
#include <hip/hip_fp16.h>
#include <stdint.h>

typedef _Float16 half_t;
typedef __attribute__((ext_vector_type(8))) _Float16 half8;   // MFMA A/B frag (4 VGPRs)
typedef __attribute__((ext_vector_type(16))) float f32x16;    // 32x32 MFMA C/D frag
typedef __attribute__((ext_vector_type(4)))  float float4v;

#define BM 128
#define BN 128
#define BK 64   // 8 chunks of 8 halves (16 B) per row

// ---------------------------------------------------------------------------
// fp32 -> fp16 RNE quantize == reference _quantize (e5m10, RNE, HW denormals).
// 16 elems/thread.
// ---------------------------------------------------------------------------
__global__ void quant_f32_to_f16(const float* __restrict__ in,
                                 half_t* __restrict__ out, long n) {
    long i = ((long)blockIdx.x * blockDim.x + threadIdx.x) * 16;
    if (i + 16 <= n) {
        float4v v0 = *(const float4v*)(in + i);
        float4v v1 = *(const float4v*)(in + i + 4);
        float4v v2 = *(const float4v*)(in + i + 8);
        float4v v3 = *(const float4v*)(in + i + 12);
        half8 h0, h1;
        h0[0]=(half_t)v0[0]; h0[1]=(half_t)v0[1]; h0[2]=(half_t)v0[2]; h0[3]=(half_t)v0[3];
        h0[4]=(half_t)v1[0]; h0[5]=(half_t)v1[1]; h0[6]=(half_t)v1[2]; h0[7]=(half_t)v1[3];
        h1[0]=(half_t)v2[0]; h1[1]=(half_t)v2[1]; h1[2]=(half_t)v2[2]; h1[3]=(half_t)v2[3];
        h1[4]=(half_t)v3[0]; h1[5]=(half_t)v3[1]; h1[6]=(half_t)v3[2]; h1[7]=(half_t)v3[3];
        *(half8*)(out + i) = h0;
        *(half8*)(out + i + 8) = h1;
    } else {
        for (; i < n && i >= 0; ++i) out[i] = (half_t)in[i];
    }
}

__device__ __forceinline__ void gld_lds16(const void* g, void* l) {
    __builtin_amdgcn_global_load_lds(
        (const __attribute__((address_space(1))) void*)g,
        (__attribute__((address_space(3))) void*)l, 16, 0, 0);
}

// ---------------------------------------------------------------------------
// C[m][n] = sum_k A[m][k]*B[n][k] + q(bias[n]).  Both operands K-contiguous.
// 128x128 tile, BK=64, 4 waves (2x2 of 64x64), mfma_f32_32x32x16_f16 (2x2
// tiles/wave), XOR bank swizzle: LDS chunk (row,pos) holds k-chunk
// pos^(row&7); fragment reads then hit all 8 bank-groups (min 4-way b128).
// global_load_lds dest stays wave-uniform base + lane*16 (we permute the
// global SOURCE per lane, which coalescing tolerates).
// FUSED variant converts fp32 during manual staging (fallback if ws small).
// ---------------------------------------------------------------------------
template <bool FUSED>
__global__ __launch_bounds__(256)
void gemm_qf16(const void* __restrict__ Av, const void* __restrict__ Bv,
               const float* __restrict__ bias, float* __restrict__ C,
               int M, int N, int K) {
    __shared__ half_t sA[BM * BK];   // 16 KB
    __shared__ half_t sB[BN * BK];   // 16 KB

    const int t    = threadIdx.x;
    const int lane = t & 63;
    const int wave = t >> 6;
    const int wm   = (wave >> 1) * 64;
    const int wn   = (wave & 1) * 64;
    const int bm   = blockIdx.y * BM;
    const int bn   = blockIdx.x * BN;

    // staging: 1024 16B-chunks per matrix, 4 per thread; chunk index c:
    // row = c>>3, LDS pos = c&7, global k-chunk = (c&7) ^ (row&7)
    int srow[4], skc[4];
    #pragma unroll
    for (int s = 0; s < 4; ++s) {
        const int c = t + 256 * s;
        srow[s] = c >> 3;
        skc[s]  = (c & 7) ^ (srow[s] & 7);
    }

    f32x16 acc[2][2] = {};

    const int ml = lane & 31;   // m (or n) within 32-tile
    const int kg = lane >> 5;   // which 8-k half of the MFMA's K=16
    const int sw = ml & 7;      // row component of the XOR swizzle

    for (int k0 = 0; k0 < K; k0 += BK) {
        if constexpr (!FUSED) {
            const half_t* A = (const half_t*)Av;
            const half_t* B = (const half_t*)Bv;
            #pragma unroll
            for (int s = 0; s < 4; ++s) {
                const long ga = (long)(bm + srow[s]) * K + k0 + skc[s] * 8;
                const long gb = (long)(bn + srow[s]) * K + k0 + skc[s] * 8;
                gld_lds16(A + ga, &sA[(t + 256 * s) * 8]);
                gld_lds16(B + gb, &sB[(t + 256 * s) * 8]);
            }
        } else {
            const float* A = (const float*)Av;
            const float* B = (const float*)Bv;
            #pragma unroll
            for (int s = 0; s < 4; ++s) {
                const long ga = (long)(bm + srow[s]) * K + k0 + skc[s] * 8;
                const long gb = (long)(bn + srow[s]) * K + k0 + skc[s] * 8;
                float4v a0 = *(const float4v*)(A + ga);
                float4v a1 = *(const float4v*)(A + ga + 4);
                float4v b0 = *(const float4v*)(B + gb);
                float4v b1 = *(const float4v*)(B + gb + 4);
                half8 ha, hb;
                ha[0]=(half_t)a0[0]; ha[1]=(half_t)a0[1]; ha[2]=(half_t)a0[2]; ha[3]=(half_t)a0[3];
                ha[4]=(half_t)a1[0]; ha[5]=(half_t)a1[1]; ha[6]=(half_t)a1[2]; ha[7]=(half_t)a1[3];
                hb[0]=(half_t)b0[0]; hb[1]=(half_t)b0[1]; hb[2]=(half_t)b0[2]; hb[3]=(half_t)b0[3];
                hb[4]=(half_t)b1[0]; hb[5]=(half_t)b1[1]; hb[6]=(half_t)b1[2]; hb[7]=(half_t)b1[3];
                *(half8*)&sA[(t + 256 * s) * 8] = ha;
                *(half8*)&sB[(t + 256 * s) * 8] = hb;
            }
        }
        __syncthreads();

        #pragma unroll
        for (int ks = 0; ks < 4; ++ks) {
            const int cp = 2 * ks + kg;                    // k-chunk 0..7
            const int pa0 = ((wm      + ml) * 8 + (cp ^ sw)) * 8;
            const int pa1 = ((wm + 32 + ml) * 8 + (cp ^ sw)) * 8;
            const int pb0 = ((wn      + ml) * 8 + (cp ^ sw)) * 8;
            const int pb1 = ((wn + 32 + ml) * 8 + (cp ^ sw)) * 8;
            half8 a0 = *(const half8*)&sA[pa0];
            half8 a1 = *(const half8*)&sA[pa1];
            half8 b0 = *(const half8*)&sB[pb0];
            half8 b1 = *(const half8*)&sB[pb1];
            acc[0][0] = __builtin_amdgcn_mfma_f32_32x32x16_f16(a0, b0, acc[0][0], 0, 0, 0);
            acc[0][1] = __builtin_amdgcn_mfma_f32_32x32x16_f16(a0, b1, acc[0][1], 0, 0, 0);
            acc[1][0] = __builtin_amdgcn_mfma_f32_32x32x16_f16(a1, b0, acc[1][0], 0, 0, 0);
            acc[1][1] = __builtin_amdgcn_mfma_f32_32x32x16_f16(a1, b1, acc[1][1], 0, 0, 0);
        }
        __syncthreads();
    }

    // Epilogue. 32x32 C/D layout [m74/m101]: col = lane&31,
    // row = (reg&3) + 8*(reg>>2) + 4*(lane>>5)
    const int cl = lane & 31;
    const int rb = 4 * (lane >> 5);
    #pragma unroll
    for (int j = 0; j < 2; ++j) {
        const int col = bn + wn + j * 32 + cl;
        const float bq = (float)(half_t)bias[col];   // inline bias quantize
        #pragma unroll
        for (int i = 0; i < 2; ++i) {
            #pragma unroll
            for (int r = 0; r < 16; ++r) {
                const int row = bm + wm + i * 32 + (r & 3) + 8 * (r >> 2) + rb;
                C[(long)row * N + col] = acc[i][j][r] + bq;
            }
        }
    }
}

extern "C" void kernel_launch(void* const* d_in, const int* in_sizes, int n_in,
                              void* d_out, int out_size, void* d_ws, size_t ws_size,
                              hipStream_t stream) {
    const float* x    = (const float*)d_in[0];
    const float* w    = (const float*)d_in[1];
    const float* bias = (const float*)d_in[2];
    float* out = (float*)d_out;

    const int OUT = in_sizes[2];
    const int IN  = in_sizes[1] / OUT;
    const int M   = in_sizes[0] / IN;
    const int N   = OUT, K = IN;

    dim3 grid(N / BN, M / BM);
    const size_t needed = ((size_t)M * K + (size_t)N * K) * sizeof(half_t);

    if (ws_size >= needed) {
        half_t* qa = (half_t*)d_ws;
        half_t* qb = qa + (size_t)M * K;
        const long na = (long)M * K, nb = (long)N * K;
        const long per = 16L * 256;
        quant_f32_to_f16<<<(int)((na + per - 1) / per), 256, 0, stream>>>(x, qa, na);
        quant_f32_to_f16<<<(int)((nb + per - 1) / per), 256, 0, stream>>>(w, qb, nb);
        gemm_qf16<false><<<grid, 256, 0, stream>>>(qa, qb, bias, out, M, N, K);
    } else {
        gemm_qf16<true><<<grid, 256, 0, stream>>>(x, w, bias, out, M, N, K);
    }
}

// Round 3
// 314.380 us; speedup vs baseline: 1.1445x; 1.0147x over previous
//
#include <hip/hip_runtime.h>
#include <hip/hip_fp16.h>
#include <stdint.h>

typedef _Float16 half_t;
typedef __attribute__((ext_vector_type(4))) _Float16 half4;   // 8 B store
typedef __attribute__((ext_vector_type(8))) _Float16 half8;   // MFMA A/B frag (4 VGPRs)
typedef __attribute__((ext_vector_type(16))) float f32x16;    // 32x32 MFMA C/D frag
typedef __attribute__((ext_vector_type(4)))  float float4v;

#define BM 128
#define BN 128
#define BK 64   // 8 chunks of 8 halves (16 B) per row

// ---------------------------------------------------------------------------
// fp32 -> fp16 RNE quantize == reference _quantize (e5m10, RNE, HW denormals).
// Canonical streaming pattern: 16 B/lane load, lane-contiguous (m13 layout),
// 8 B/lane store. One float4 per thread.
// ---------------------------------------------------------------------------
__global__ void quant_f32_to_f16(const float* __restrict__ in,
                                 half_t* __restrict__ out, long n4) {
    const long i = (long)blockIdx.x * blockDim.x + threadIdx.x;
    if (i < n4) {
        float4v v = ((const float4v*)in)[i];
        half4 h;
        h[0] = (half_t)v[0]; h[1] = (half_t)v[1];
        h[2] = (half_t)v[2]; h[3] = (half_t)v[3];
        ((half4*)out)[i] = h;
    }
}

__device__ __forceinline__ void gld_lds16(const void* g, void* l) {
    __builtin_amdgcn_global_load_lds(
        (const __attribute__((address_space(1))) void*)g,
        (__attribute__((address_space(3))) void*)l, 16, 0, 0);
}

// ---------------------------------------------------------------------------
// C[m][n] = sum_k A[m][k]*B[n][k] + q(bias[n]).  Both operands K-contiguous.
// 128x128 tile, BK=64, 4 waves (2x2 of 64x64), mfma_f32_32x32x16_f16 (2x2
// tiles/wave), XOR chunk swizzle (kept: free, VALUBusy only 11%).
// Note: SQ_LDS_BANK_CONFLICT ~1.68e7 here is the structural multi-phase cost
// of wave64 ds_read_b128 (8 word-accesses/bank minimum) — NOT fixable
// conflicts; R1 (unswizzled 16x16) showed the identical count.
// FUSED variant converts fp32 during manual staging (fallback if ws small).
// ---------------------------------------------------------------------------
template <bool FUSED>
__global__ __launch_bounds__(256)
void gemm_qf16(const void* __restrict__ Av, const void* __restrict__ Bv,
               const float* __restrict__ bias, float* __restrict__ C,
               int M, int N, int K) {
    __shared__ half_t sA[BM * BK];   // 16 KB
    __shared__ half_t sB[BN * BK];   // 16 KB

    const int t    = threadIdx.x;
    const int lane = t & 63;
    const int wave = t >> 6;
    const int wm   = (wave >> 1) * 64;
    const int wn   = (wave & 1) * 64;
    const int bm   = blockIdx.y * BM;
    const int bn   = blockIdx.x * BN;

    // staging: 1024 16B-chunks per matrix, 4 per thread; chunk index c:
    // row = c>>3, LDS pos = c&7, global k-chunk = (c&7) ^ (row&7)
    int srow[4], skc[4];
    #pragma unroll
    for (int s = 0; s < 4; ++s) {
        const int c = t + 256 * s;
        srow[s] = c >> 3;
        skc[s]  = (c & 7) ^ (srow[s] & 7);
    }

    f32x16 acc[2][2] = {};

    const int ml = lane & 31;   // m (or n) within 32-tile
    const int kg = lane >> 5;   // which 8-k half of the MFMA's K=16
    const int sw = ml & 7;      // row component of the XOR swizzle

    for (int k0 = 0; k0 < K; k0 += BK) {
        if constexpr (!FUSED) {
            const half_t* A = (const half_t*)Av;
            const half_t* B = (const half_t*)Bv;
            #pragma unroll
            for (int s = 0; s < 4; ++s) {
                const long ga = (long)(bm + srow[s]) * K + k0 + skc[s] * 8;
                const long gb = (long)(bn + srow[s]) * K + k0 + skc[s] * 8;
                gld_lds16(A + ga, &sA[(t + 256 * s) * 8]);
                gld_lds16(B + gb, &sB[(t + 256 * s) * 8]);
            }
        } else {
            const float* A = (const float*)Av;
            const float* B = (const float*)Bv;
            #pragma unroll
            for (int s = 0; s < 4; ++s) {
                const long ga = (long)(bm + srow[s]) * K + k0 + skc[s] * 8;
                const long gb = (long)(bn + srow[s]) * K + k0 + skc[s] * 8;
                float4v a0 = *(const float4v*)(A + ga);
                float4v a1 = *(const float4v*)(A + ga + 4);
                float4v b0 = *(const float4v*)(B + gb);
                float4v b1 = *(const float4v*)(B + gb + 4);
                half8 ha, hb;
                ha[0]=(half_t)a0[0]; ha[1]=(half_t)a0[1]; ha[2]=(half_t)a0[2]; ha[3]=(half_t)a0[3];
                ha[4]=(half_t)a1[0]; ha[5]=(half_t)a1[1]; ha[6]=(half_t)a1[2]; ha[7]=(half_t)a1[3];
                hb[0]=(half_t)b0[0]; hb[1]=(half_t)b0[1]; hb[2]=(half_t)b0[2]; hb[3]=(half_t)b0[3];
                hb[4]=(half_t)b1[0]; hb[5]=(half_t)b1[1]; hb[6]=(half_t)b1[2]; hb[7]=(half_t)b1[3];
                *(half8*)&sA[(t + 256 * s) * 8] = ha;
                *(half8*)&sB[(t + 256 * s) * 8] = hb;
            }
        }
        __syncthreads();

        #pragma unroll
        for (int ks = 0; ks < 4; ++ks) {
            const int cp = 2 * ks + kg;                    // k-chunk 0..7
            const int pa0 = ((wm      + ml) * 8 + (cp ^ sw)) * 8;
            const int pa1 = ((wm + 32 + ml) * 8 + (cp ^ sw)) * 8;
            const int pb0 = ((wn      + ml) * 8 + (cp ^ sw)) * 8;
            const int pb1 = ((wn + 32 + ml) * 8 + (cp ^ sw)) * 8;
            half8 a0 = *(const half8*)&sA[pa0];
            half8 a1 = *(const half8*)&sA[pa1];
            half8 b0 = *(const half8*)&sB[pb0];
            half8 b1 = *(const half8*)&sB[pb1];
            acc[0][0] = __builtin_amdgcn_mfma_f32_32x32x16_f16(a0, b0, acc[0][0], 0, 0, 0);
            acc[0][1] = __builtin_amdgcn_mfma_f32_32x32x16_f16(a0, b1, acc[0][1], 0, 0, 0);
            acc[1][0] = __builtin_amdgcn_mfma_f32_32x32x16_f16(a1, b0, acc[1][0], 0, 0, 0);
            acc[1][1] = __builtin_amdgcn_mfma_f32_32x32x16_f16(a1, b1, acc[1][1], 0, 0, 0);
        }
        __syncthreads();
    }

    // Epilogue. 32x32 C/D layout [m74/m101]: col = lane&31,
    // row = (reg&3) + 8*(reg>>2) + 4*(lane>>5)
    const int cl = lane & 31;
    const int rb = 4 * (lane >> 5);
    #pragma unroll
    for (int j = 0; j < 2; ++j) {
        const int col = bn + wn + j * 32 + cl;
        const float bq = (float)(half_t)bias[col];   // inline bias quantize
        #pragma unroll
        for (int i = 0; i < 2; ++i) {
            #pragma unroll
            for (int r = 0; r < 16; ++r) {
                const int row = bm + wm + i * 32 + (r & 3) + 8 * (r >> 2) + rb;
                C[(long)row * N + col] = acc[i][j][r] + bq;
            }
        }
    }
}

extern "C" void kernel_launch(void* const* d_in, const int* in_sizes, int n_in,
                              void* d_out, int out_size, void* d_ws, size_t ws_size,
                              hipStream_t stream) {
    const float* x    = (const float*)d_in[0];
    const float* w    = (const float*)d_in[1];
    const float* bias = (const float*)d_in[2];
    float* out = (float*)d_out;

    const int OUT = in_sizes[2];
    const int IN  = in_sizes[1] / OUT;
    const int M   = in_sizes[0] / IN;
    const int N   = OUT, K = IN;

    dim3 grid(N / BN, M / BM);
    const size_t needed = ((size_t)M * K + (size_t)N * K) * sizeof(half_t);

    if (ws_size >= needed) {
        half_t* qa = (half_t*)d_ws;
        half_t* qb = qa + (size_t)M * K;
        const long na4 = (long)M * K / 4, nb4 = (long)N * K / 4;
        quant_f32_to_f16<<<(int)((na4 + 255) / 256), 256, 0, stream>>>(x, qa, na4);
        quant_f32_to_f16<<<(int)((nb4 + 255) / 256), 256, 0, stream>>>(w, qb, nb4);
        gemm_qf16<false><<<grid, 256, 0, stream>>>(qa, qb, bias, out, M, N, K);
    } else {
        gemm_qf16<true><<<grid, 256, 0, stream>>>(x, w, bias, out, M, N, K);
    }
}

// Round 4
// 313.219 us; speedup vs baseline: 1.1487x; 1.0037x over previous
//
#include <hip/hip_runtime.h>
#include <hip/hip_fp16.h>
#include <stdint.h>

typedef _Float16 half_t;
typedef __attribute__((ext_vector_type(8))) _Float16 half8;   // MFMA A/B frag (4 VGPRs)
typedef __attribute__((ext_vector_type(16))) float f32x16;    // 32x32 MFMA C/D frag
typedef __attribute__((ext_vector_type(4)))  float float4v;

#define BM 128
#define BN 128
#define BK 64   // 8 chunks of 8 halves (16 B) per row

// ---------------------------------------------------------------------------
// Merged fp32->fp16 RNE quantize for BOTH tensors in one dispatch.
// == reference _quantize (e5m10, RNE, HW denormals). 8 elems/thread,
// 2x dwordx4 loads + 1x dwordx4 store (R1's empirically-best gap pattern).
// Output is contiguous (qa then qb in d_ws); input branches at na.
// ---------------------------------------------------------------------------
__global__ void quant_both(const float* __restrict__ inA,
                           const float* __restrict__ inB,
                           half_t* __restrict__ out, long na, long ntot) {
    long i = ((long)blockIdx.x * blockDim.x + threadIdx.x) * 8;
    if (i + 8 > ntot) {
        for (; i < ntot; ++i)
            out[i] = (half_t)(i < na ? inA[i] : inB[i - na]);
        return;
    }
    const float* src = (i < na) ? (inA + i) : (inB + (i - na));
    float4v v0 = *(const float4v*)(src);
    float4v v1 = *(const float4v*)(src + 4);
    half8 h;
    h[0] = (half_t)v0[0]; h[1] = (half_t)v0[1];
    h[2] = (half_t)v0[2]; h[3] = (half_t)v0[3];
    h[4] = (half_t)v1[0]; h[5] = (half_t)v1[1];
    h[6] = (half_t)v1[2]; h[7] = (half_t)v1[3];
    *(half8*)(out + i) = h;
}

__device__ __forceinline__ void gld_lds16(const void* g, void* l) {
    __builtin_amdgcn_global_load_lds(
        (const __attribute__((address_space(1))) void*)g,
        (__attribute__((address_space(3))) void*)l, 16, 0, 0);
}

// ---------------------------------------------------------------------------
// C[m][n] = sum_k A[m][k]*B[n][k] + q(bias[n]).  Both operands K-contiguous.
// 128x128 tile, BK=64, 4 waves (2x2 of 64x64), mfma_f32_32x32x16_f16,
// XOR chunk swizzle on LDS k-chunks.
// Block swizzle: all (M/BM)*(N/BN) blocks are co-resident; block b -> XCD b&7
// (round-robin assumption, perf-only); each XCD owns a 4-wide bn strip so its
// B working set = 4*BN*K*2B = 4 MB = one XCD L2.
// SQ_LDS_BANK_CONFLICT ~1.68e7 here is the structural multi-phase cost of
// wave64 ds_read_b128 (8 word-accesses/bank min) — not fixable; measured
// identical across unswizzled 16x16 (R1) and swizzled 32x32 (R2).
// ---------------------------------------------------------------------------
template <bool FUSED>
__global__ __launch_bounds__(256)
void gemm_qf16(const void* __restrict__ Av, const void* __restrict__ Bv,
               const float* __restrict__ bias, float* __restrict__ C,
               int M, int N, int K) {
    __shared__ half_t sA[BM * BK];   // 16 KB
    __shared__ half_t sB[BN * BK];   // 16 KB

    const int t    = threadIdx.x;
    const int lane = t & 63;
    const int wave = t >> 6;
    const int wm   = (wave >> 1) * 64;
    const int wn   = (wave & 1) * 64;

    // XCD-aware 1-D -> 2-D block swizzle (specialized for the 32x32 grid)
    const int nbx = N / BN, nby = M / BM;
    int bxi, byi;
    {
        const int b = blockIdx.x;
        if (nbx == 32 && nby == 32) {
            const int xcd = b & 7;
            const int s   = b >> 3;
            bxi = xcd * 4 + (s & 3);   // bn strip of 4 per XCD
            byi = s >> 2;
        } else {
            bxi = b % nbx;
            byi = b / nbx;
        }
    }
    const int bm = byi * BM;
    const int bn = bxi * BN;

    // staging: 1024 16B-chunks per matrix, 4 per thread; chunk index c:
    // row = c>>3, LDS pos = c&7, global k-chunk = (c&7) ^ (row&7)
    int srow[4], skc[4];
    #pragma unroll
    for (int s = 0; s < 4; ++s) {
        const int c = t + 256 * s;
        srow[s] = c >> 3;
        skc[s]  = (c & 7) ^ (srow[s] & 7);
    }

    f32x16 acc[2][2] = {};

    const int ml = lane & 31;   // m (or n) within 32-tile
    const int kg = lane >> 5;   // which 8-k half of the MFMA's K=16
    const int sw = ml & 7;      // row component of the XOR swizzle

    for (int k0 = 0; k0 < K; k0 += BK) {
        if constexpr (!FUSED) {
            const half_t* A = (const half_t*)Av;
            const half_t* B = (const half_t*)Bv;
            #pragma unroll
            for (int s = 0; s < 4; ++s) {
                const long ga = (long)(bm + srow[s]) * K + k0 + skc[s] * 8;
                const long gb = (long)(bn + srow[s]) * K + k0 + skc[s] * 8;
                gld_lds16(A + ga, &sA[(t + 256 * s) * 8]);
                gld_lds16(B + gb, &sB[(t + 256 * s) * 8]);
            }
        } else {
            const float* A = (const float*)Av;
            const float* B = (const float*)Bv;
            #pragma unroll
            for (int s = 0; s < 4; ++s) {
                const long ga = (long)(bm + srow[s]) * K + k0 + skc[s] * 8;
                const long gb = (long)(bn + srow[s]) * K + k0 + skc[s] * 8;
                float4v a0 = *(const float4v*)(A + ga);
                float4v a1 = *(const float4v*)(A + ga + 4);
                float4v b0 = *(const float4v*)(B + gb);
                float4v b1 = *(const float4v*)(B + gb + 4);
                half8 ha, hb;
                ha[0]=(half_t)a0[0]; ha[1]=(half_t)a0[1]; ha[2]=(half_t)a0[2]; ha[3]=(half_t)a0[3];
                ha[4]=(half_t)a1[0]; ha[5]=(half_t)a1[1]; ha[6]=(half_t)a1[2]; ha[7]=(half_t)a1[3];
                hb[0]=(half_t)b0[0]; hb[1]=(half_t)b0[1]; hb[2]=(half_t)b0[2]; hb[3]=(half_t)b0[3];
                hb[4]=(half_t)b1[0]; hb[5]=(half_t)b1[1]; hb[6]=(half_t)b1[2]; hb[7]=(half_t)b1[3];
                *(half8*)&sA[(t + 256 * s) * 8] = ha;
                *(half8*)&sB[(t + 256 * s) * 8] = hb;
            }
        }
        __syncthreads();

        #pragma unroll
        for (int ks = 0; ks < 4; ++ks) {
            const int cp = 2 * ks + kg;                    // k-chunk 0..7
            const int pa0 = ((wm      + ml) * 8 + (cp ^ sw)) * 8;
            const int pa1 = ((wm + 32 + ml) * 8 + (cp ^ sw)) * 8;
            const int pb0 = ((wn      + ml) * 8 + (cp ^ sw)) * 8;
            const int pb1 = ((wn + 32 + ml) * 8 + (cp ^ sw)) * 8;
            half8 a0 = *(const half8*)&sA[pa0];
            half8 a1 = *(const half8*)&sA[pa1];
            half8 b0 = *(const half8*)&sB[pb0];
            half8 b1 = *(const half8*)&sB[pb1];
            acc[0][0] = __builtin_amdgcn_mfma_f32_32x32x16_f16(a0, b0, acc[0][0], 0, 0, 0);
            acc[0][1] = __builtin_amdgcn_mfma_f32_32x32x16_f16(a0, b1, acc[0][1], 0, 0, 0);
            acc[1][0] = __builtin_amdgcn_mfma_f32_32x32x16_f16(a1, b0, acc[1][0], 0, 0, 0);
            acc[1][1] = __builtin_amdgcn_mfma_f32_32x32x16_f16(a1, b1, acc[1][1], 0, 0, 0);
        }
        __syncthreads();
    }

    // Epilogue. 32x32 C/D layout [m74/m101]: col = lane&31,
    // row = (reg&3) + 8*(reg>>2) + 4*(lane>>5)
    const int cl = lane & 31;
    const int rb = 4 * (lane >> 5);
    #pragma unroll
    for (int j = 0; j < 2; ++j) {
        const int col = bn + wn + j * 32 + cl;
        const float bq = (float)(half_t)bias[col];   // inline bias quantize
        #pragma unroll
        for (int i = 0; i < 2; ++i) {
            #pragma unroll
            for (int r = 0; r < 16; ++r) {
                const int row = bm + wm + i * 32 + (r & 3) + 8 * (r >> 2) + rb;
                C[(long)row * N + col] = acc[i][j][r] + bq;
            }
        }
    }
}

extern "C" void kernel_launch(void* const* d_in, const int* in_sizes, int n_in,
                              void* d_out, int out_size, void* d_ws, size_t ws_size,
                              hipStream_t stream) {
    const float* x    = (const float*)d_in[0];
    const float* w    = (const float*)d_in[1];
    const float* bias = (const float*)d_in[2];
    float* out = (float*)d_out;

    const int OUT = in_sizes[2];
    const int IN  = in_sizes[1] / OUT;
    const int M   = in_sizes[0] / IN;
    const int N   = OUT, K = IN;

    dim3 grid((N / BN) * (M / BM));
    const size_t needed = ((size_t)M * K + (size_t)N * K) * sizeof(half_t);

    if (ws_size >= needed) {
        half_t* q = (half_t*)d_ws;          // qa at 0, qb at M*K (contiguous)
        const long na = (long)M * K, ntot = na + (long)N * K;
        const long per = 8L * 256;
        quant_both<<<(int)((ntot + per - 1) / per), 256, 0, stream>>>(x, w, q, na, ntot);
        gemm_qf16<false><<<grid, 256, 0, stream>>>(q, q + na, bias, out, M, N, K);
    } else {
        gemm_qf16<true><<<grid, 256, 0, stream>>>(x, w, bias, out, M, N, K);
    }
}